// Round 20
// baseline (168.319 us; speedup 1.0000x reference)
//
#include <hip/hip_runtime.h>
#include <hip/hip_bf16.h>

typedef _Float16 f16_t;
typedef unsigned short u16;
typedef unsigned int u32;
typedef float f32x4 __attribute__((ext_vector_type(4)));
typedef f16_t f16x8 __attribute__((ext_vector_type(8)));
typedef u16 u16x8 __attribute__((ext_vector_type(8)));
typedef u16 u16x4 __attribute__((ext_vector_type(4)));
typedef u32 u32x4 __attribute__((ext_vector_type(4)));

#define MROWS 4096
#define NHEADS 4
#define COUT 64
#define OHF 256   // NHEADS*COUT
#define NCLS 40
#define LOG2E 1.4426950408889634f
#define PLD 264   // partial row length (u16): 256 acc + 4 rowsum + pad

static __device__ __forceinline__ u16 f16b(float x) {
    return __builtin_bit_cast(u16, (f16_t)x);
}
static __device__ __forceinline__ float f16f(u16 x) {
    return (float)__builtin_bit_cast(f16_t, x);
}
static __device__ __forceinline__ float dmu_decode(u32 ku) {
    const u32 fb = (ku & 0x80000000u) ? (ku ^ 0x80000000u) : ~ku;
    return __builtin_bit_cast(float, fb);
}
static __device__ __forceinline__ float wave_sum(float v) {
    v += __shfl_xor(v, 1);  v += __shfl_xor(v, 2);  v += __shfl_xor(v, 4);
    v += __shfl_xor(v, 8);  v += __shfl_xor(v, 16); v += __shfl_xor(v, 32);
    return v;
}

// ---------------- prep: Cw/cbf, va1/vc1, va2/vc2, dmu (260 blocks, all wave-parallel) ----------------
__global__ __launch_bounds__(256) void prep_kernel(const float* __restrict__ W1w,
                                                   const float* __restrict__ W1b,
                                                   const float* __restrict__ a1,
                                                   const float* __restrict__ W2w,
                                                   const float* __restrict__ W2b,
                                                   const float* __restrict__ W3w,
                                                   const float* __restrict__ W3b,
                                                   const float* __restrict__ a2,
                                                   float* __restrict__ Cwf,
                                                   float* __restrict__ cbf,
                                                   float* __restrict__ va1,
                                                   float* __restrict__ vc1,
                                                   float* __restrict__ va2,
                                                   float* __restrict__ vc2,
                                                   u32* __restrict__ dmu) {
    __shared__ float u[8][64];
    const int bx = blockIdx.x, tid = threadIdx.x;
    const int lane = tid & 63, wv = tid >> 6;
    if (bx < 256) {
        float acc = 0.f;
        for (int t = 0; t < 64; ++t)
            acc += W2w[bx * 64 + t] * W3w[t * 256 + tid];
        Cwf[bx * 256 + tid] = acc;
        if (tid < 64) {
            float pb = W2w[bx * 64 + tid] * W3b[tid];
            pb = wave_sum(pb);
            if (tid == 0) cbf[bx] = pb + W2b[bx];
        }
    } else if (bx < 258) {
        const int k = (bx - 256) * 256 + tid;
#pragma unroll
        for (int hs = 0; hs < 8; ++hs) {
            const int h = hs >> 1, s = hs & 1;
            float acc = 0.f;
            for (int c = 0; c < COUT; ++c)
                acc += W1w[(size_t)(h * COUT + c) * 512 + k] * a1[h * 128 + s * COUT + c];
            va1[hs * 512 + k] = acc;
        }
        {
            const int hs = (bx - 256) * 4 + wv;
            const int h = hs >> 1, s = hs & 1;
            float pb = W1b[h * COUT + lane] * a1[h * 128 + s * COUT + lane];
            pb = wave_sum(pb);
            if (lane == 0) vc1[hs] = pb;
        }
    } else if (bx == 258) {
#pragma unroll
        for (int e = tid * 2; e < tid * 2 + 2; ++e) {
            const int hs = e >> 6, t = e & 63;
            const int h = hs >> 1, s = hs & 1;
            float acc = 0.f;
            for (int c = 0; c < COUT; ++c)
                acc += W2w[(size_t)(h * COUT + c) * 64 + t] * a2[h * 128 + s * COUT + c];
            u[hs][t] = acc;
        }
        __syncthreads();
#pragma unroll
        for (int hs = 0; hs < 8; ++hs) {
            float acc = 0.f;
            for (int t = 0; t < 64; ++t) acc += u[hs][t] * W3w[t * 256 + tid];
            va2[hs * 256 + tid] = acc;
        }
#pragma unroll
        for (int rep = 0; rep < 2; ++rep) {
            const int hs = wv + rep * 4;
            const int h = hs >> 1, s = hs & 1;
            float pb = u[hs][lane] * W3b[lane] +
                       W2b[h * COUT + lane] * a2[h * 128 + s * COUT + lane];
            pb = wave_sum(pb);
            if (lane == 0) vc2[hs] = pb;
        }
    } else {
        if (tid < 8) dmu[tid] = 0u;   // monotone-mapped -inf
    }
}

// ---------------- work: heterogeneous grid {bits 0..nbits-1 | gemm | srcdst} ----------------
// bits FIRST: memory-bound A-scan saturates CUs immediately; compute blocks backfill and overlap.
// gemm -> fragment-major WhF: chunk (jb,c,g) = 8 f16 of Wh^T[c][jb*32+8g..+8] at ((jb*256+c)*4+g)*8
__global__ __launch_bounds__(256) void work_kernel(const float* __restrict__ X,
                                                   const float* __restrict__ Bm,
                                                   const float* __restrict__ bias,
                                                   int K, int nbits,
                                                   u16* __restrict__ WhF,
                                                   const float* __restrict__ va,
                                                   const float* __restrict__ vc,
                                                   float* __restrict__ srcT,
                                                   float* __restrict__ dstT,
                                                   u32* __restrict__ dmu,
                                                   const int* __restrict__ A,
                                                   u32* __restrict__ AbitsT) {
    __shared__ __align__(16) unsigned char smem[19456];   // union arena
    const int bx = blockIdx.x, tid = threadIdx.x;
    if (bx < nbits) {
        // ---- bits: 2 rows per block, int4 loads + nibble + LDS assembly ----
        u32 (*nib)[1024] = (u32(*)[1024])smem;
        const int i0 = bx * 2;
        u32 nb[8];
#pragma unroll
        for (int q = 0; q < 8; ++q) {
            const int r = q >> 2;
            const int col = (q & 3) * 1024 + tid * 4;
            const int4 v = *(const int4*)&A[(size_t)(i0 + r) * MROWS + col];
            nb[q] = (u32)(v.x != 0) | ((u32)(v.y != 0) << 1) |
                    ((u32)(v.z != 0) << 2) | ((u32)(v.w != 0) << 3);
        }
#pragma unroll
        for (int q = 0; q < 8; ++q)
            nib[q >> 2][(q & 3) * 256 + tid] = nb[q];
        __syncthreads();
        {
            const int r = tid >> 7, jw = tid & 127;
            const u32x4 n0 = *(const u32x4*)&nib[r][8 * jw];
            const u32x4 n1 = *(const u32x4*)&nib[r][8 * jw + 4];
            u32 word = n0[0] | (n0[1] << 4) | (n0[2] << 8) | (n0[3] << 12) |
                       (n1[0] << 16) | (n1[1] << 20) | (n1[2] << 24) | (n1[3] << 28);
            AbitsT[(size_t)jw * MROWS + i0 + r] = word;
        }
        return;
    }
    const int bxx = bx - nbits;
    if (bxx < 256) {
        // ---- GEMM -> fragment-major WhF ----
        u16 (*Al)[40] = (u16(*)[40])smem;
        u16 (*Bl)[40] = (u16(*)[40])(smem + 5120);
        u16 (*Tl)[72] = (u16(*)[72])(smem + 10240);
        const int lane = tid & 63, wv = tid >> 6;
        const int l15 = lane & 15, g = lane >> 4;
        const int m0 = (bxx & 63) * 64, n0 = (bxx >> 6) * 64;
        const int r = tid >> 2, c8 = (tid & 3) * 8;
        f32x4 acc[4] = {};
        for (int k0 = 0; k0 < K; k0 += 32) {
            const float4 a0 = *(const float4*)&X[(size_t)(m0 + r) * K + k0 + c8];
            const float4 a1 = *(const float4*)&X[(size_t)(m0 + r) * K + k0 + c8 + 4];
            const float4 b0 = *(const float4*)&Bm[(size_t)(n0 + r) * K + k0 + c8];
            const float4 b1 = *(const float4*)&Bm[(size_t)(n0 + r) * K + k0 + c8 + 4];
            u16x8 av, bv;
            av[0] = f16b(a0.x); av[1] = f16b(a0.y); av[2] = f16b(a0.z); av[3] = f16b(a0.w);
            av[4] = f16b(a1.x); av[5] = f16b(a1.y); av[6] = f16b(a1.z); av[7] = f16b(a1.w);
            bv[0] = f16b(b0.x); bv[1] = f16b(b0.y); bv[2] = f16b(b0.z); bv[3] = f16b(b0.w);
            bv[4] = f16b(b1.x); bv[5] = f16b(b1.y); bv[6] = f16b(b1.z); bv[7] = f16b(b1.w);
            __syncthreads();
            *(u16x8*)&Al[r][c8] = av;
            *(u16x8*)&Bl[r][c8] = bv;
            __syncthreads();
            f16x8 afr = *(const f16x8*)&Al[16 * wv + l15][8 * g];
#pragma unroll
            for (int ni = 0; ni < 4; ++ni) {
                f16x8 bfr = *(const f16x8*)&Bl[16 * ni + l15][8 * g];
                acc[ni] = __builtin_amdgcn_mfma_f32_16x16x32_f16(afr, bfr, acc[ni], 0, 0, 0);
            }
        }
#pragma unroll
        for (int ni = 0; ni < 4; ++ni) {
            const int nl = 16 * ni + l15;
            const float bvs = bias[n0 + nl];
#pragma unroll
            for (int rr = 0; rr < 4; ++rr)
                Tl[nl][16 * wv + 4 * g + rr] = f16b(acc[ni][rr] + bvs);
        }
        __syncthreads();
        const int jb0 = m0 >> 5;
#pragma unroll
        for (int q = 0; q < 2; ++q) {
            const int id = tid + 256 * q;
            const int jb_l = id >> 8, rem = id & 255;
            const int c_l = rem >> 2, gf = rem & 3;
            u16x8 v = *(const u16x8*)&Tl[c_l][32 * jb_l + 8 * gf];
            *(u16x8*)&WhF[(size_t)(((jb0 + jb_l) * 256 + n0 + c_l) * 4 + gf) * 8] = v;
        }
        return;
    }
    // ---- srcdst: 16 rows x 16 k-slices + fused per-head dst max ----
    float (*red)[16][9] = (float(*)[16][9])smem;
    float (*dred)[16]   = (float(*)[16])(smem + 9216);
    const int bs = bxx - 256;
    const int ii = tid >> 4, ki = tid & 15;
    const int i = bs * 16 + ii;
    const int KS = K >> 4;
    const int k0 = ki * KS;
    float acc[8] = {};
    for (int k = k0; k < k0 + KS; k += 4) {
        const float4 xv = *(const float4*)&X[(size_t)i * K + k];
#pragma unroll
        for (int hs = 0; hs < 8; ++hs) {
            const float4 vv = *(const float4*)&va[(size_t)hs * K + k];
            acc[hs] += xv.x * vv.x + xv.y * vv.y + xv.z * vv.z + xv.w * vv.w;
        }
    }
#pragma unroll
    for (int hs = 0; hs < 8; ++hs) red[ii][ki][hs] = acc[hs];
    __syncthreads();
    if (tid < 128) {
        const int row = tid >> 3, hs = tid & 7, h = hs >> 1;
        float sum = 0.f;
#pragma unroll
        for (int kk = 0; kk < 16; ++kk) sum += red[row][kk][hs];
        const float val = sum + vc[hs];
        const int ig = bs * 16 + row;
        if ((hs & 1) == 0) {
            srcT[h * MROWS + ig] = val;
        } else {
            dstT[h * MROWS + ig] = val;
            dred[h][row] = val;
        }
    }
    __syncthreads();
    if (tid < 4) {
        float m = -3.4e38f;
#pragma unroll
        for (int r = 0; r < 16; ++r) m = fmaxf(m, dred[tid][r]);
        const u32 b = __builtin_bit_cast(u32, m);
        const u32 key = (b & 0x80000000u) ? ~b : (b | 0x80000000u);
        atomicMax(dmu + tid, key);
    }
}

// ---------------- attention: AbitsT masking, pipelined prefetch, wave=(h,mi), setprio ----------------
// w' = mask ? max(F1_i*G1_j, F2_i*G2_j) : 0   (= exp(lrelu(s+d) - C_i); all factors <= 1)
template <int JT>
__global__ __launch_bounds__(512, 4) void attn_kernel(const u16* __restrict__ WhF,
                                                      const float* __restrict__ srcT,
                                                      const float* __restrict__ dstT,
                                                      const u32* __restrict__ AbitsT,
                                                      const u32* __restrict__ dmu,
                                                      u16* __restrict__ partial,
                                                      float* __restrict__ outF) {
    constexpr int J64 = JT * 64;                    // j's per chunk
    constexpr int NSTEP = 2 * JT;                   // 32-j steps
    __shared__ __align__(16) float GT[8 * J64];     // [(h*2+br)][j] f32 exps
    const int tid = threadIdx.x;
    const int lane = tid & 63, w = tid >> 6;
    const int h = w & 3, mi = w >> 2;               // wave = (head, mi-group)
    const int l15 = lane & 15, g = lane >> 4;
    const int i0 = blockIdx.x * 32;
    const int chunk = blockIdx.y;
    const int jbase = chunk * J64;

    // ---- prologue: G tables (once per block) ----
    for (int e = tid; e < 8 * J64; e += 512) {
        const int hb = e / J64;                     // h*2 + br
        const int j = e - hb * J64;
        const float dmhe = dmu_decode(dmu[hb >> 1]);
        const float sc = (hb & 1) ? 0.01f * LOG2E : LOG2E;
        GT[e] = __builtin_amdgcn_exp2f((dstT[(hb >> 1) * MROWS + jbase + j] - dmhe) * sc);
    }

    // ---- per-row F factors ----
    const float dmh = dmu_decode(dmu[h]);
    const float s = srcT[h * MROWS + i0 + 16 * mi + l15];
    const float sd = s + dmh;
    const float C = fmaxf(sd, 0.01f * sd);
    const float F1 = __builtin_amdgcn_exp2f((sd - C) * LOG2E);
    const float F2 = __builtin_amdgcn_exp2f((0.01f * sd - C) * LOG2E);
    __syncthreads();   // GT ready; no barriers after this point

    f32x4 acc[4] = {};
    f32x4 acc1 = {};
    f16x8 ones;
#pragma unroll
    for (int e = 0; e < 8; ++e) ones[e] = (f16_t)1.0f;
    const int irow = i0 + 16 * mi + l15;
    const int jb0 = jbase >> 5;
    const int cb = h * COUT + l15;                  // c for ni: cb + 16*ni

    // ---- software pipeline: prefetch step 0 ----
    u32 curW = AbitsT[(size_t)jb0 * MROWS + irow];
    f16x8 cB0 = *(const f16x8*)&WhF[(size_t)((((jb0) << 8) + cb) * 4 + g) * 8];
    f16x8 cB1 = *(const f16x8*)&WhF[(size_t)((((jb0) << 8) + cb + 16) * 4 + g) * 8];
    f16x8 cB2 = *(const f16x8*)&WhF[(size_t)((((jb0) << 8) + cb + 32) * 4 + g) * 8];
    f16x8 cB3 = *(const f16x8*)&WhF[(size_t)((((jb0) << 8) + cb + 48) * 4 + g) * 8];

#pragma unroll
    for (int t = 0; t < NSTEP; ++t) {
        // prefetch step t+1 (registers; renamed by unroll)
        u32 nW = 0;
        f16x8 nB0 = {}, nB1 = {}, nB2 = {}, nB3 = {};
        if (t + 1 < NSTEP) {
            const int jb = jb0 + t + 1;
            nW = AbitsT[(size_t)jb * MROWS + irow];
            nB0 = *(const f16x8*)&WhF[(size_t)(((jb << 8) + cb) * 4 + g) * 8];
            nB1 = *(const f16x8*)&WhF[(size_t)(((jb << 8) + cb + 16) * 4 + g) * 8];
            nB2 = *(const f16x8*)&WhF[(size_t)(((jb << 8) + cb + 32) * 4 + g) * 8];
            nB3 = *(const f16x8*)&WhF[(size_t)(((jb << 8) + cb + 48) * 4 + g) * 8];
        }
        // scores for step t (GT in LDS, mask in register)
        const int goff = t * 32 + 8 * g;
        const float4 g10 = *(const float4*)&GT[(h * 2) * J64 + goff];
        const float4 g11 = *(const float4*)&GT[(h * 2) * J64 + goff + 4];
        const float4 g20 = *(const float4*)&GT[(h * 2 + 1) * J64 + goff];
        const float4 g21 = *(const float4*)&GT[(h * 2 + 1) * J64 + goff + 4];
        const float G1[8] = {g10.x, g10.y, g10.z, g10.w, g11.x, g11.y, g11.z, g11.w};
        const float G2[8] = {g20.x, g20.y, g20.z, g20.w, g21.x, g21.y, g21.z, g21.w};
        const u32 bits = (curW >> (8 * g)) & 0xffu;
        f16x8 a;
#pragma unroll
        for (int e = 0; e < 8; ++e) {
            float wv = fmaxf(G1[e] * F1, G2[e] * F2);
            wv = ((bits >> e) & 1u) ? wv : 0.f;
            a[e] = (f16_t)wv;
        }
        __builtin_amdgcn_s_setprio(1);
        acc[0] = __builtin_amdgcn_mfma_f32_16x16x32_f16(a, cB0, acc[0], 0, 0, 0);
        acc[1] = __builtin_amdgcn_mfma_f32_16x16x32_f16(a, cB1, acc[1], 0, 0, 0);
        acc[2] = __builtin_amdgcn_mfma_f32_16x16x32_f16(a, cB2, acc[2], 0, 0, 0);
        acc[3] = __builtin_amdgcn_mfma_f32_16x16x32_f16(a, cB3, acc[3], 0, 0, 0);
        acc1 = __builtin_amdgcn_mfma_f32_16x16x32_f16(a, ones, acc1, 0, 0, 0);
        __builtin_amdgcn_s_setprio(0);
        curW = nW;
        cB0 = nB0; cB1 = nB1; cB2 = nB2; cB3 = nB3;
    }

    if (partial) {
        u16* pc = partial + (size_t)chunk * MROWS * PLD;
#pragma unroll
        for (int ni = 0; ni < 4; ++ni)
#pragma unroll
            for (int rr = 0; rr < 4; ++rr) {
                const int i = i0 + 16 * mi + 4 * g + rr;
                pc[(size_t)i * PLD + h * COUT + 16 * ni + l15] = f16b(acc[ni][rr]);
            }
#pragma unroll
        for (int rr = 0; rr < 4; ++rr)
            if (l15 == rr)
                pc[(size_t)(i0 + 16 * mi + 4 * g + rr) * PLD + 256 + h] = f16b(acc1[rr]);
    } else {
#pragma unroll
        for (int rr = 0; rr < 4; ++rr) {
            const int i = i0 + 16 * mi + 4 * g + rr;
            const float rs = acc1[rr];
#pragma unroll
            for (int ni = 0; ni < 4; ++ni)
                outF[(size_t)i * OHF + h * COUT + 16 * ni + l15] = acc[ni][rr] / rs;
        }
    }
}

// ---------------- combine chunked f16 partials (+ optional fused classifier) ----------------
__global__ __launch_bounds__(256) void combine_kernel(const u16* __restrict__ partial,
                                                      int nchunk,
                                                      float* __restrict__ outF,
                                                      const float* __restrict__ FLw,
                                                      const float* __restrict__ FLb,
                                                      float* __restrict__ outL) {
    __shared__ float xrow[256];
    __shared__ float cred[40][4];
    const int i = blockIdx.x, c = threadIdx.x, h = c >> 6;
    float v = 0.f, rs = 0.f;
    for (int ch = 0; ch < nchunk; ++ch) {
        const u16* pc = partial + (size_t)ch * MROWS * PLD + (size_t)i * PLD;
        v += f16f(pc[c]);
        rs += f16f(pc[256 + h]);
    }
    const float r = v / rs;
    outF[(size_t)i * OHF + c] = r;
    if (!FLw) return;
    xrow[c] = r;
    __syncthreads();
    if (c < 160) {
        const int k = c >> 2, seg = c & 3;
        const float* xp = &xrow[seg * 64];
        const float* wp = &FLw[(size_t)k * OHF + seg * 64];
        float a = 0.f;
#pragma unroll
        for (int t = 0; t < 64; t += 4) {
            const float4 x4 = *(const float4*)&xp[t];
            const float4 w4 = *(const float4*)&wp[t];
            a += x4.x * w4.x + x4.y * w4.y + x4.z * w4.z + x4.w * w4.w;
        }
        cred[k][seg] = a;
    }
    __syncthreads();
    if (c < NCLS)
        outL[(size_t)i * NCLS + c] = cred[c][0] + cred[c][1] + cred[c][2] + cred[c][3] + FLb[c];
}

extern "C" void kernel_launch(void* const* d_in, const int* in_sizes, int n_in,
                              void* d_out, int out_size, void* d_ws, size_t ws_size,
                              hipStream_t stream) {
    const float* hIn = (const float*)d_in[0];
    const int*   A   = (const int*)d_in[1];
    const float* W1w = (const float*)d_in[2];
    const float* W1b = (const float*)d_in[3];
    const float* a1  = (const float*)d_in[4];
    const float* W3w = (const float*)d_in[5];
    const float* W3b = (const float*)d_in[6];
    const float* W2w = (const float*)d_in[7];
    const float* W2b = (const float*)d_in[8];
    const float* a2  = (const float*)d_in[9];
    const float* FLw = (const float*)d_in[10];
    const float* FLb = (const float*)d_in[11];
    float* outX = (float*)d_out;                     // x: (4096 x 256) fp32
    float* outL = outX + (size_t)MROWS * OHF;        // logits: (4096 x 40) fp32

    char* p = (char*)d_ws;
    auto alloc = [&](size_t bytes) { char* q = p; p += (bytes + 255) & ~(size_t)255; return q; };
    u32*   AbitsT = (u32*)alloc((size_t)MROWS * 128 * 4);
    u16*   WhF1  = (u16*)alloc((size_t)OHF * MROWS * 2);
    u16*   WhF2  = (u16*)alloc((size_t)OHF * MROWS * 2);
    float* x1f   = (float*)alloc((size_t)MROWS * OHF * 4);
    float* Cwf   = (float*)alloc((size_t)256 * 256 * 4);
    float* cbf   = (float*)alloc(256 * 4);
    float* va1   = (float*)alloc((size_t)8 * 512 * 4);
    float* vc1   = (float*)alloc(8 * 4);
    float* va2   = (float*)alloc((size_t)8 * 256 * 4);
    float* vc2   = (float*)alloc(8 * 4);
    float* srcT1 = (float*)alloc((size_t)NHEADS * MROWS * 4);
    float* dstT1 = (float*)alloc((size_t)NHEADS * MROWS * 4);
    float* srcT2 = (float*)alloc((size_t)NHEADS * MROWS * 4);
    float* dstT2 = (float*)alloc((size_t)NHEADS * MROWS * 4);
    u32*   dmu   = (u32*)alloc(8 * 4);               // [0..3]=layer1, [4..7]=layer2
    const int nchunk = 4;                            // f16 partials: 4 * 4096 * 264 * 2 = 8.65 MB
    u16* partial = (u16*)p;

    dim3 blk(256);
    prep_kernel<<<dim3(260), blk, 0, stream>>>(W1w, W1b, a1, W2w, W2b, W3w, W3b, a2,
                                               Cwf, cbf, va1, vc1, va2, vc2, dmu);

    // ---- layer 1: bits (first, memory-bound) + gemm + srcdst in one dispatch ----
    work_kernel<<<dim3(2560), blk, 0, stream>>>(hIn, W1w, W1b, 512, 2048, WhF1,
                                                va1, vc1, srcT1, dstT1, dmu,
                                                A, AbitsT);
    attn_kernel<16><<<dim3(128, nchunk), dim3(512), 0, stream>>>(
        WhF1, srcT1, dstT1, AbitsT, dmu, partial, nullptr);
    combine_kernel<<<dim3(4096), blk, 0, stream>>>(partial, nchunk, x1f,
                                                   nullptr, nullptr, nullptr);

    // ---- layer 2 (W3∘W2 fused into Cwf; scores exact from x1f via va2); no bits blocks ----
    work_kernel<<<dim3(512), blk, 0, stream>>>(x1f, Cwf, cbf, 256, 0, WhF2,
                                               va2, vc2, srcT2, dstT2, dmu + 4,
                                               A, AbitsT);
    attn_kernel<16><<<dim3(128, nchunk), dim3(512), 0, stream>>>(
        WhF2, srcT2, dstT2, AbitsT, dmu + 4, partial, nullptr);
    combine_kernel<<<dim3(4096), blk, 0, stream>>>(partial, nchunk, outX,
                                                   FLw, FLb, outL);
}

// Round 21
// 161.655 us; speedup vs baseline: 1.0412x; 1.0412x over previous
//
#include <hip/hip_runtime.h>
#include <hip/hip_bf16.h>

typedef _Float16 f16_t;
typedef unsigned short u16;
typedef unsigned int u32;
typedef float f32x4 __attribute__((ext_vector_type(4)));
typedef f16_t f16x8 __attribute__((ext_vector_type(8)));
typedef u16 u16x8 __attribute__((ext_vector_type(8)));
typedef u16 u16x4 __attribute__((ext_vector_type(4)));
typedef u32 u32x4 __attribute__((ext_vector_type(4)));

#define MROWS 4096
#define NHEADS 4
#define COUT 64
#define OHF 256   // NHEADS*COUT
#define NCLS 40
#define LOG2E 1.4426950408889634f
#define PLD 264   // partial row length (u16): 256 acc + 4 rowsum + pad

static __device__ __forceinline__ u16 f16b(float x) {
    return __builtin_bit_cast(u16, (f16_t)x);
}
static __device__ __forceinline__ float f16f(u16 x) {
    return (float)__builtin_bit_cast(f16_t, x);
}
static __device__ __forceinline__ float dmu_decode(u32 ku) {
    const u32 fb = (ku & 0x80000000u) ? (ku ^ 0x80000000u) : ~ku;
    return __builtin_bit_cast(float, fb);
}
static __device__ __forceinline__ float wave_sum(float v) {
    v += __shfl_xor(v, 1);  v += __shfl_xor(v, 2);  v += __shfl_xor(v, 4);
    v += __shfl_xor(v, 8);  v += __shfl_xor(v, 16); v += __shfl_xor(v, 32);
    return v;
}

// ---------------- prep: Cw/cbf, va1/vc1, va2/vc2, dmu (260 blocks, all wave-parallel) ----------------
__global__ __launch_bounds__(256) void prep_kernel(const float* __restrict__ W1w,
                                                   const float* __restrict__ W1b,
                                                   const float* __restrict__ a1,
                                                   const float* __restrict__ W2w,
                                                   const float* __restrict__ W2b,
                                                   const float* __restrict__ W3w,
                                                   const float* __restrict__ W3b,
                                                   const float* __restrict__ a2,
                                                   float* __restrict__ Cwf,
                                                   float* __restrict__ cbf,
                                                   float* __restrict__ va1,
                                                   float* __restrict__ vc1,
                                                   float* __restrict__ va2,
                                                   float* __restrict__ vc2,
                                                   u32* __restrict__ dmu) {
    __shared__ float u[8][64];
    const int bx = blockIdx.x, tid = threadIdx.x;
    const int lane = tid & 63, wv = tid >> 6;
    if (bx < 256) {
        float acc = 0.f;
        for (int t = 0; t < 64; ++t)
            acc += W2w[bx * 64 + t] * W3w[t * 256 + tid];
        Cwf[bx * 256 + tid] = acc;
        if (tid < 64) {
            float pb = W2w[bx * 64 + tid] * W3b[tid];
            pb = wave_sum(pb);
            if (tid == 0) cbf[bx] = pb + W2b[bx];
        }
    } else if (bx < 258) {
        const int k = (bx - 256) * 256 + tid;
#pragma unroll
        for (int hs = 0; hs < 8; ++hs) {
            const int h = hs >> 1, s = hs & 1;
            float acc = 0.f;
            for (int c = 0; c < COUT; ++c)
                acc += W1w[(size_t)(h * COUT + c) * 512 + k] * a1[h * 128 + s * COUT + c];
            va1[hs * 512 + k] = acc;
        }
        {
            const int hs = (bx - 256) * 4 + wv;
            const int h = hs >> 1, s = hs & 1;
            float pb = W1b[h * COUT + lane] * a1[h * 128 + s * COUT + lane];
            pb = wave_sum(pb);
            if (lane == 0) vc1[hs] = pb;
        }
    } else if (bx == 258) {
#pragma unroll
        for (int e = tid * 2; e < tid * 2 + 2; ++e) {
            const int hs = e >> 6, t = e & 63;
            const int h = hs >> 1, s = hs & 1;
            float acc = 0.f;
            for (int c = 0; c < COUT; ++c)
                acc += W2w[(size_t)(h * COUT + c) * 64 + t] * a2[h * 128 + s * COUT + c];
            u[hs][t] = acc;
        }
        __syncthreads();
#pragma unroll
        for (int hs = 0; hs < 8; ++hs) {
            float acc = 0.f;
            for (int t = 0; t < 64; ++t) acc += u[hs][t] * W3w[t * 256 + tid];
            va2[hs * 256 + tid] = acc;
        }
#pragma unroll
        for (int rep = 0; rep < 2; ++rep) {
            const int hs = wv + rep * 4;
            const int h = hs >> 1, s = hs & 1;
            float pb = u[hs][lane] * W3b[lane] +
                       W2b[h * COUT + lane] * a2[h * 128 + s * COUT + lane];
            pb = wave_sum(pb);
            if (lane == 0) vc2[hs] = pb;
        }
    } else {
        if (tid < 8) dmu[tid] = 0u;   // monotone-mapped -inf
    }
}

// ---------------- work: heterogeneous grid {gemm 0..255 | srcdst 256..511 | bits 512..} ----------------
// gemm -> fragment-major WhF: chunk (jb,c,g) = 8 f16 of Wh^T[c][jb*32+8g..+8] at ((jb*256+c)*4+g)*8
__global__ __launch_bounds__(256) void work_kernel(const float* __restrict__ X,
                                                   const float* __restrict__ Bm,
                                                   const float* __restrict__ bias,
                                                   int K,
                                                   u16* __restrict__ WhF,
                                                   const float* __restrict__ va,
                                                   const float* __restrict__ vc,
                                                   float* __restrict__ srcT,
                                                   float* __restrict__ dstT,
                                                   u32* __restrict__ dmu,
                                                   const int* __restrict__ A,
                                                   u32* __restrict__ AbitsT) {
    __shared__ __align__(16) unsigned char smem[19456];   // union arena
    const int bx = blockIdx.x, tid = threadIdx.x;
    if (bx >= 512) {
        // ---- bits: 2 rows per block, int4 loads + nibble + LDS assembly ----
        u32 (*nib)[1024] = (u32(*)[1024])smem;
        const int i0 = (bx - 512) * 2;
        u32 nb[8];
#pragma unroll
        for (int q = 0; q < 8; ++q) {
            const int r = q >> 2;
            const int col = (q & 3) * 1024 + tid * 4;
            const int4 v = *(const int4*)&A[(size_t)(i0 + r) * MROWS + col];
            nb[q] = (u32)(v.x != 0) | ((u32)(v.y != 0) << 1) |
                    ((u32)(v.z != 0) << 2) | ((u32)(v.w != 0) << 3);
        }
#pragma unroll
        for (int q = 0; q < 8; ++q)
            nib[q >> 2][(q & 3) * 256 + tid] = nb[q];
        __syncthreads();
        {
            const int r = tid >> 7, jw = tid & 127;
            const u32x4 n0 = *(const u32x4*)&nib[r][8 * jw];
            const u32x4 n1 = *(const u32x4*)&nib[r][8 * jw + 4];
            u32 word = n0[0] | (n0[1] << 4) | (n0[2] << 8) | (n0[3] << 12) |
                       (n1[0] << 16) | (n1[1] << 20) | (n1[2] << 24) | (n1[3] << 28);
            AbitsT[(size_t)jw * MROWS + i0 + r] = word;
        }
        return;
    }
    if (bx < 256) {
        // ---- GEMM -> fragment-major WhF ----
        u16 (*Al)[40] = (u16(*)[40])smem;
        u16 (*Bl)[40] = (u16(*)[40])(smem + 5120);
        u16 (*Tl)[72] = (u16(*)[72])(smem + 10240);
        const int lane = tid & 63, wv = tid >> 6;
        const int l15 = lane & 15, g = lane >> 4;
        const int m0 = (bx & 63) * 64, n0 = (bx >> 6) * 64;
        const int r = tid >> 2, c8 = (tid & 3) * 8;
        f32x4 acc[4] = {};
        for (int k0 = 0; k0 < K; k0 += 32) {
            const float4 a0 = *(const float4*)&X[(size_t)(m0 + r) * K + k0 + c8];
            const float4 a1 = *(const float4*)&X[(size_t)(m0 + r) * K + k0 + c8 + 4];
            const float4 b0 = *(const float4*)&Bm[(size_t)(n0 + r) * K + k0 + c8];
            const float4 b1 = *(const float4*)&Bm[(size_t)(n0 + r) * K + k0 + c8 + 4];
            u16x8 av, bv;
            av[0] = f16b(a0.x); av[1] = f16b(a0.y); av[2] = f16b(a0.z); av[3] = f16b(a0.w);
            av[4] = f16b(a1.x); av[5] = f16b(a1.y); av[6] = f16b(a1.z); av[7] = f16b(a1.w);
            bv[0] = f16b(b0.x); bv[1] = f16b(b0.y); bv[2] = f16b(b0.z); bv[3] = f16b(b0.w);
            bv[4] = f16b(b1.x); bv[5] = f16b(b1.y); bv[6] = f16b(b1.z); bv[7] = f16b(b1.w);
            __syncthreads();
            *(u16x8*)&Al[r][c8] = av;
            *(u16x8*)&Bl[r][c8] = bv;
            __syncthreads();
            f16x8 afr = *(const f16x8*)&Al[16 * wv + l15][8 * g];
#pragma unroll
            for (int ni = 0; ni < 4; ++ni) {
                f16x8 bfr = *(const f16x8*)&Bl[16 * ni + l15][8 * g];
                acc[ni] = __builtin_amdgcn_mfma_f32_16x16x32_f16(afr, bfr, acc[ni], 0, 0, 0);
            }
        }
#pragma unroll
        for (int ni = 0; ni < 4; ++ni) {
            const int nl = 16 * ni + l15;
            const float bvs = bias[n0 + nl];
#pragma unroll
            for (int rr = 0; rr < 4; ++rr)
                Tl[nl][16 * wv + 4 * g + rr] = f16b(acc[ni][rr] + bvs);
        }
        __syncthreads();
        const int jb0 = m0 >> 5;
#pragma unroll
        for (int q = 0; q < 2; ++q) {
            const int id = tid + 256 * q;
            const int jb_l = id >> 8, rem = id & 255;
            const int c_l = rem >> 2, gf = rem & 3;
            u16x8 v = *(const u16x8*)&Tl[c_l][32 * jb_l + 8 * gf];
            *(u16x8*)&WhF[(size_t)(((jb0 + jb_l) * 256 + n0 + c_l) * 4 + gf) * 8] = v;
        }
        return;
    }
    // ---- srcdst: 16 rows x 16 k-slices + fused per-head dst max ----
    float (*red)[16][9] = (float(*)[16][9])smem;
    float (*dred)[16]   = (float(*)[16])(smem + 9216);
    const int bs = bx - 256;
    const int ii = tid >> 4, ki = tid & 15;
    const int i = bs * 16 + ii;
    const int KS = K >> 4;
    const int k0 = ki * KS;
    float acc[8] = {};
    for (int k = k0; k < k0 + KS; k += 4) {
        const float4 xv = *(const float4*)&X[(size_t)i * K + k];
#pragma unroll
        for (int hs = 0; hs < 8; ++hs) {
            const float4 vv = *(const float4*)&va[(size_t)hs * K + k];
            acc[hs] += xv.x * vv.x + xv.y * vv.y + xv.z * vv.z + xv.w * vv.w;
        }
    }
#pragma unroll
    for (int hs = 0; hs < 8; ++hs) red[ii][ki][hs] = acc[hs];
    __syncthreads();
    if (tid < 128) {
        const int row = tid >> 3, hs = tid & 7, h = hs >> 1;
        float sum = 0.f;
#pragma unroll
        for (int kk = 0; kk < 16; ++kk) sum += red[row][kk][hs];
        const float val = sum + vc[hs];
        const int ig = bs * 16 + row;
        if ((hs & 1) == 0) {
            srcT[h * MROWS + ig] = val;
        } else {
            dstT[h * MROWS + ig] = val;
            dred[h][row] = val;
        }
    }
    __syncthreads();
    if (tid < 4) {
        float m = -3.4e38f;
#pragma unroll
        for (int r = 0; r < 16; ++r) m = fmaxf(m, dred[tid][r]);
        const u32 b = __builtin_bit_cast(u32, m);
        const u32 key = (b & 0x80000000u) ? ~b : (b | 0x80000000u);
        atomicMax(dmu + tid, key);
    }
}

// ---------------- attention: AbitsT masking, pipelined prefetch, wave=(h,mi), setprio ----------------
// w' = mask ? max(F1_i*G1_j, F2_i*G2_j) : 0   (= exp(lrelu(s+d) - C_i); all factors <= 1)
template <int JT>
__global__ __launch_bounds__(512, 4) void attn_kernel(const u16* __restrict__ WhF,
                                                      const float* __restrict__ srcT,
                                                      const float* __restrict__ dstT,
                                                      const u32* __restrict__ AbitsT,
                                                      const u32* __restrict__ dmu,
                                                      u16* __restrict__ partial,
                                                      float* __restrict__ outF) {
    constexpr int J64 = JT * 64;                    // j's per chunk
    constexpr int NSTEP = 2 * JT;                   // 32-j steps
    __shared__ __align__(16) float GT[8 * J64];     // [(h*2+br)][j] f32 exps
    const int tid = threadIdx.x;
    const int lane = tid & 63, w = tid >> 6;
    const int h = w & 3, mi = w >> 2;               // wave = (head, mi-group)
    const int l15 = lane & 15, g = lane >> 4;
    const int i0 = blockIdx.x * 32;
    const int chunk = blockIdx.y;
    const int jbase = chunk * J64;

    // ---- prologue: G tables (once per block) ----
    for (int e = tid; e < 8 * J64; e += 512) {
        const int hb = e / J64;                     // h*2 + br
        const int j = e - hb * J64;
        const float dmhe = dmu_decode(dmu[hb >> 1]);
        const float sc = (hb & 1) ? 0.01f * LOG2E : LOG2E;
        GT[e] = __builtin_amdgcn_exp2f((dstT[(hb >> 1) * MROWS + jbase + j] - dmhe) * sc);
    }

    // ---- per-row F factors ----
    const float dmh = dmu_decode(dmu[h]);
    const float s = srcT[h * MROWS + i0 + 16 * mi + l15];
    const float sd = s + dmh;
    const float C = fmaxf(sd, 0.01f * sd);
    const float F1 = __builtin_amdgcn_exp2f((sd - C) * LOG2E);
    const float F2 = __builtin_amdgcn_exp2f((0.01f * sd - C) * LOG2E);
    __syncthreads();   // GT ready; no barriers after this point

    f32x4 acc[4] = {};
    f32x4 acc1 = {};
    f16x8 ones;
#pragma unroll
    for (int e = 0; e < 8; ++e) ones[e] = (f16_t)1.0f;
    const int irow = i0 + 16 * mi + l15;
    const int jb0 = jbase >> 5;
    const int cb = h * COUT + l15;                  // c for ni: cb + 16*ni

    // ---- software pipeline: prefetch step 0 ----
    u32 curW = AbitsT[(size_t)jb0 * MROWS + irow];
    f16x8 cB0 = *(const f16x8*)&WhF[(size_t)((((jb0) << 8) + cb) * 4 + g) * 8];
    f16x8 cB1 = *(const f16x8*)&WhF[(size_t)((((jb0) << 8) + cb + 16) * 4 + g) * 8];
    f16x8 cB2 = *(const f16x8*)&WhF[(size_t)((((jb0) << 8) + cb + 32) * 4 + g) * 8];
    f16x8 cB3 = *(const f16x8*)&WhF[(size_t)((((jb0) << 8) + cb + 48) * 4 + g) * 8];

#pragma unroll
    for (int t = 0; t < NSTEP; ++t) {
        // prefetch step t+1 (registers; renamed by unroll)
        u32 nW = 0;
        f16x8 nB0 = {}, nB1 = {}, nB2 = {}, nB3 = {};
        if (t + 1 < NSTEP) {
            const int jb = jb0 + t + 1;
            nW = AbitsT[(size_t)jb * MROWS + irow];
            nB0 = *(const f16x8*)&WhF[(size_t)(((jb << 8) + cb) * 4 + g) * 8];
            nB1 = *(const f16x8*)&WhF[(size_t)(((jb << 8) + cb + 16) * 4 + g) * 8];
            nB2 = *(const f16x8*)&WhF[(size_t)(((jb << 8) + cb + 32) * 4 + g) * 8];
            nB3 = *(const f16x8*)&WhF[(size_t)(((jb << 8) + cb + 48) * 4 + g) * 8];
        }
        // scores for step t (GT in LDS, mask in register)
        const int goff = t * 32 + 8 * g;
        const float4 g10 = *(const float4*)&GT[(h * 2) * J64 + goff];
        const float4 g11 = *(const float4*)&GT[(h * 2) * J64 + goff + 4];
        const float4 g20 = *(const float4*)&GT[(h * 2 + 1) * J64 + goff];
        const float4 g21 = *(const float4*)&GT[(h * 2 + 1) * J64 + goff + 4];
        const float G1[8] = {g10.x, g10.y, g10.z, g10.w, g11.x, g11.y, g11.z, g11.w};
        const float G2[8] = {g20.x, g20.y, g20.z, g20.w, g21.x, g21.y, g21.z, g21.w};
        const u32 bits = (curW >> (8 * g)) & 0xffu;
        f16x8 a;
#pragma unroll
        for (int e = 0; e < 8; ++e) {
            float wv = fmaxf(G1[e] * F1, G2[e] * F2);
            wv = ((bits >> e) & 1u) ? wv : 0.f;
            a[e] = (f16_t)wv;
        }
        __builtin_amdgcn_s_setprio(1);
        acc[0] = __builtin_amdgcn_mfma_f32_16x16x32_f16(a, cB0, acc[0], 0, 0, 0);
        acc[1] = __builtin_amdgcn_mfma_f32_16x16x32_f16(a, cB1, acc[1], 0, 0, 0);
        acc[2] = __builtin_amdgcn_mfma_f32_16x16x32_f16(a, cB2, acc[2], 0, 0, 0);
        acc[3] = __builtin_amdgcn_mfma_f32_16x16x32_f16(a, cB3, acc[3], 0, 0, 0);
        acc1 = __builtin_amdgcn_mfma_f32_16x16x32_f16(a, ones, acc1, 0, 0, 0);
        __builtin_amdgcn_s_setprio(0);
        curW = nW;
        cB0 = nB0; cB1 = nB1; cB2 = nB2; cB3 = nB3;
    }

    if (partial) {
        u16* pc = partial + (size_t)chunk * MROWS * PLD;
#pragma unroll
        for (int ni = 0; ni < 4; ++ni)
#pragma unroll
            for (int rr = 0; rr < 4; ++rr) {
                const int i = i0 + 16 * mi + 4 * g + rr;
                pc[(size_t)i * PLD + h * COUT + 16 * ni + l15] = f16b(acc[ni][rr]);
            }
#pragma unroll
        for (int rr = 0; rr < 4; ++rr)
            if (l15 == rr)
                pc[(size_t)(i0 + 16 * mi + 4 * g + rr) * PLD + 256 + h] = f16b(acc1[rr]);
    } else {
#pragma unroll
        for (int rr = 0; rr < 4; ++rr) {
            const int i = i0 + 16 * mi + 4 * g + rr;
            const float rs = acc1[rr];
#pragma unroll
            for (int ni = 0; ni < 4; ++ni)
                outF[(size_t)i * OHF + h * COUT + 16 * ni + l15] = acc[ni][rr] / rs;
        }
    }
}

// ---------------- combine chunked f16 partials (+ optional fused classifier) ----------------
__global__ __launch_bounds__(256) void combine_kernel(const u16* __restrict__ partial,
                                                      int nchunk,
                                                      float* __restrict__ outF,
                                                      const float* __restrict__ FLw,
                                                      const float* __restrict__ FLb,
                                                      float* __restrict__ outL) {
    __shared__ float xrow[256];
    __shared__ float cred[40][4];
    const int i = blockIdx.x, c = threadIdx.x, h = c >> 6;
    float v = 0.f, rs = 0.f;
    for (int ch = 0; ch < nchunk; ++ch) {
        const u16* pc = partial + (size_t)ch * MROWS * PLD + (size_t)i * PLD;
        v += f16f(pc[c]);
        rs += f16f(pc[256 + h]);
    }
    const float r = v / rs;
    outF[(size_t)i * OHF + c] = r;
    if (!FLw) return;
    xrow[c] = r;
    __syncthreads();
    if (c < 160) {
        const int k = c >> 2, seg = c & 3;
        const float* xp = &xrow[seg * 64];
        const float* wp = &FLw[(size_t)k * OHF + seg * 64];
        float a = 0.f;
#pragma unroll
        for (int t = 0; t < 64; t += 4) {
            const float4 x4 = *(const float4*)&xp[t];
            const float4 w4 = *(const float4*)&wp[t];
            a += x4.x * w4.x + x4.y * w4.y + x4.z * w4.z + x4.w * w4.w;
        }
        cred[k][seg] = a;
    }
    __syncthreads();
    if (c < NCLS)
        outL[(size_t)i * NCLS + c] = cred[c][0] + cred[c][1] + cred[c][2] + cred[c][3] + FLb[c];
}

extern "C" void kernel_launch(void* const* d_in, const int* in_sizes, int n_in,
                              void* d_out, int out_size, void* d_ws, size_t ws_size,
                              hipStream_t stream) {
    const float* hIn = (const float*)d_in[0];
    const int*   A   = (const int*)d_in[1];
    const float* W1w = (const float*)d_in[2];
    const float* W1b = (const float*)d_in[3];
    const float* a1  = (const float*)d_in[4];
    const float* W3w = (const float*)d_in[5];
    const float* W3b = (const float*)d_in[6];
    const float* W2w = (const float*)d_in[7];
    const float* W2b = (const float*)d_in[8];
    const float* a2  = (const float*)d_in[9];
    const float* FLw = (const float*)d_in[10];
    const float* FLb = (const float*)d_in[11];
    float* outX = (float*)d_out;                     // x: (4096 x 256) fp32
    float* outL = outX + (size_t)MROWS * OHF;        // logits: (4096 x 40) fp32

    char* p = (char*)d_ws;
    auto alloc = [&](size_t bytes) { char* q = p; p += (bytes + 255) & ~(size_t)255; return q; };
    u32*   AbitsT = (u32*)alloc((size_t)MROWS * 128 * 4);
    u16*   WhF1  = (u16*)alloc((size_t)OHF * MROWS * 2);
    u16*   WhF2  = (u16*)alloc((size_t)OHF * MROWS * 2);
    float* x1f   = (float*)alloc((size_t)MROWS * OHF * 4);
    float* Cwf   = (float*)alloc((size_t)256 * 256 * 4);
    float* cbf   = (float*)alloc(256 * 4);
    float* va1   = (float*)alloc((size_t)8 * 512 * 4);
    float* vc1   = (float*)alloc(8 * 4);
    float* va2   = (float*)alloc((size_t)8 * 256 * 4);
    float* vc2   = (float*)alloc(8 * 4);
    float* srcT1 = (float*)alloc((size_t)NHEADS * MROWS * 4);
    float* dstT1 = (float*)alloc((size_t)NHEADS * MROWS * 4);
    float* srcT2 = (float*)alloc((size_t)NHEADS * MROWS * 4);
    float* dstT2 = (float*)alloc((size_t)NHEADS * MROWS * 4);
    u32*   dmu   = (u32*)alloc(8 * 4);               // [0..3]=layer1, [4..7]=layer2
    const int nchunk = 4;                            // f16 partials: 4 * 4096 * 264 * 2 = 8.65 MB
    u16* partial = (u16*)p;

    dim3 blk(256);
    prep_kernel<<<dim3(260), blk, 0, stream>>>(W1w, W1b, a1, W2w, W2b, W3w, W3b, a2,
                                               Cwf, cbf, va1, vc1, va2, vc2, dmu);

    // ---- layer 1: gemm + srcdst + bits(A->AbitsT) in one heterogeneous dispatch ----
    work_kernel<<<dim3(2560), blk, 0, stream>>>(hIn, W1w, W1b, 512, WhF1,
                                                va1, vc1, srcT1, dstT1, dmu,
                                                A, AbitsT);
    attn_kernel<16><<<dim3(128, nchunk), dim3(512), 0, stream>>>(
        WhF1, srcT1, dstT1, AbitsT, dmu, partial, nullptr);
    combine_kernel<<<dim3(4096), blk, 0, stream>>>(partial, nchunk, x1f,
                                                   nullptr, nullptr, nullptr);

    // ---- layer 2 (W3∘W2 fused into Cwf; scores exact from x1f via va2); no bits blocks ----
    work_kernel<<<dim3(512), blk, 0, stream>>>(x1f, Cwf, cbf, 256, WhF2,
                                               va2, vc2, srcT2, dstT2, dmu + 4,
                                               A, AbitsT);
    attn_kernel<16><<<dim3(128, nchunk), dim3(512), 0, stream>>>(
        WhF2, srcT2, dstT2, AbitsT, dmu + 4, partial, nullptr);
    combine_kernel<<<dim3(4096), blk, 0, stream>>>(partial, nchunk, outX,
                                                   FLw, FLb, outL);
}